// Round 4
// baseline (4369.053 us; speedup 1.0000x reference)
//
#include <hip/hip_runtime.h>
#include <hip/hip_fp16.h>
#include <math.h>

#define DD 35
#define TT 140
#define DHX 70
#define GW 36   // padded fp16 row for final arrays (35+1), 72 B

__device__ __forceinline__ float sigf(float x){ return 1.0f/(1.0f+expf(-x)); }

// ---------------- init ----------------
__global__ void k_init(unsigned int* packed, int* bstart, int* bend,
                       float* out, const float* b2, int N, int B){
  int i = blockIdx.x*blockDim.x + threadIdx.x;
  if (i < N){ packed[i]=0u; }
  if (i < B){ bstart[i] = 0x7fffffff; bend[i] = 0; out[i] = b2[0]; }
}

// ---------------- degree count (packed: hi16=protein, lo16=ligand) ----------
__global__ void k_edge_deg(const int* __restrict__ ei, const int* __restrict__ split,
                           unsigned int* packed, int E){
  int e = blockIdx.x*blockDim.x + threadIdx.x;
  if (e >= E) return;
  int s = ei[e], d = ei[E+e];
  atomicAdd(&packed[d], (split[s]==1) ? 0x10000u : 1u);
}

// unpack degrees -> rsqrt; CSR counts; batch ranges via boundary detection
__global__ void k_node1(const unsigned int* __restrict__ packed,
                        float* dinvp, float* dinvl, int* cnt,
                        const int* __restrict__ batch,
                        int* bstart, int* bend, int N){
  int i = blockIdx.x*blockDim.x + threadIdx.x;
  if (i >= N) return;
  unsigned int p = packed[i];
  int pc = (int)(p >> 16), lc = (int)(p & 0xFFFFu);
  dinvp[i] = rsqrtf((float)(pc + 1));
  dinvl[i] = rsqrtf((float)(lc + 1));
  cnt[i] = pc + lc;
  int b = batch[i];
  if (i == 0 || batch[i-1] != b) bstart[b] = i;
  if (i == N-1 || batch[i+1] != b) bend[b] = i + 1;
}

// ---------------- exclusive scan (3 phase), 1024 elems / block ----------------
__global__ void k_scanA(const int* __restrict__ cnt, int* excl, int* bsum, int N){
  __shared__ int sh[256];
  int t = threadIdx.x;
  int base = (blockIdx.x*256 + t)*4;
  int v0 = (base+0<N)? cnt[base+0]:0;
  int v1 = (base+1<N)? cnt[base+1]:0;
  int v2 = (base+2<N)? cnt[base+2]:0;
  int v3 = (base+3<N)? cnt[base+3]:0;
  int s = v0+v1+v2+v3;
  sh[t] = s; __syncthreads();
  for (int o=1;o<256;o<<=1){
    int add = (t>=o)? sh[t-o] : 0; __syncthreads();
    sh[t] += add; __syncthreads();
  }
  int incl = sh[t];
  int ex = incl - s;
  if (t==255) bsum[blockIdx.x] = incl;
  if (base+0<N) excl[base+0]=ex;
  if (base+1<N) excl[base+1]=ex+v0;
  if (base+2<N) excl[base+2]=ex+v0+v1;
  if (base+3<N) excl[base+3]=ex+v0+v1+v2;
}

__global__ void k_scanB(int* bsum, int nb){
  __shared__ int sh[512];
  int t = threadIdx.x;
  int s = (t<nb)? bsum[t] : 0;
  sh[t]=s; __syncthreads();
  for (int o=1;o<512;o<<=1){
    int add=(t>=o)?sh[t-o]:0; __syncthreads();
    sh[t]+=add; __syncthreads();
  }
  if (t<nb) bsum[t] = sh[t]-s;
}

__global__ void k_scanC(int* rowptr, int* curP, int* curL,
                        const int* __restrict__ bsum,
                        const unsigned int* __restrict__ packed, int N, int E){
  int i = blockIdx.x*blockDim.x + threadIdx.x;
  if (i<N){
    int v = rowptr[i] + bsum[i>>10];
    rowptr[i]=v; curP[i]=v; curL[i]=v + (int)(packed[i]>>16);
  }
  if (i==0) rowptr[N] = E;
}

// ---------------- fill segmented CSR: protein edges first, 4B src index -------
__global__ void k_fill(const int* __restrict__ ei, const int* __restrict__ split,
                       int* curP, int* curL, int* eidx, int E){
  int e = blockIdx.x*blockDim.x + threadIdx.x;
  if (e >= E) return;
  int s = ei[e], d = ei[E+e];
  int pos = (split[s]==1) ? atomicAdd(&curP[d], 1) : atomicAdd(&curL[d], 1);
  eidx[pos] = s;
}

// ---------------- pack x -> fp16 gg (split-selected, dinv-premult) + own ------
__global__ void k_pack0(const float* __restrict__ x,
                        const float* __restrict__ dinvp, const float* __restrict__ dinvl,
                        const int* __restrict__ split,
                        __half* __restrict__ ggA, __half* __restrict__ ggT,
                        __half* __restrict__ ownA, __half* __restrict__ ownT, int N){
  int i = blockIdx.x*blockDim.x + threadIdx.x;
  int n = i/18, k = i - n*18;
  if (n >= N) return;
  int sp = split[n];
  float dp = dinvp[n], dl = dinvl[n];
  float dsel = sp ? dp : dl, doth = sp ? dl : dp;
  float v0, v1;
  if (k < 16){ v0 = x[(size_t)n*DD + 2*k]; v1 = x[(size_t)n*DD + 2*k + 1]; }
  else if (k == 16){ v0 = x[(size_t)n*DD + 32]; v1 = x[(size_t)n*DD + 33]; }
  else { v0 = x[(size_t)n*DD + 34]; v1 = 0.f; }
  __half2 hg = __floats2half2_rn(dsel*v0, dsel*v1);
  __half2 ho = __floats2half2_rn(doth*v0, doth*v1);
  if (k < 16){
    *(__half2*)(ggA + (size_t)n*32 + 2*k) = hg;
    *(__half2*)(ownA + (size_t)n*32 + 2*k) = ho;
  } else {
    *(__half2*)(ggT + (size_t)n*4 + 2*(k-16)) = hg;
    *(__half2*)(ownT + (size_t)n*4 + 2*(k-16)) = ho;
  }
}

// ---------------- fused GCN layer: 1-sector gathers, segmented CSR ------------
__global__ void __launch_bounds__(256)
k_gcn(const __half* __restrict__ ggA, const __half* __restrict__ ggT,
      const __half* __restrict__ ownA, const __half* __restrict__ ownT,
      __half* __restrict__ ggAo, __half* __restrict__ ggTo,
      __half* __restrict__ ownAo, __half* __restrict__ ownTo,
      __half* __restrict__ hpF, __half* __restrict__ hlF,
      const int* __restrict__ rowptr, const int* __restrict__ eidx,
      const unsigned int* __restrict__ packed, const int* __restrict__ split,
      const float* __restrict__ dinvp, const float* __restrict__ dinvl,
      const float* __restrict__ Wp, const float* __restrict__ bp,
      const float* __restrict__ Wl, const float* __restrict__ bl,
      int N, int last){
  int node = blockIdx.x*4 + (threadIdx.x>>6);
  if (node >= N) return;
  int ln = threadIdx.x & 63;
  int sub = ln & 7, g = ln >> 3;      // 8 groups of 8 lanes; group g = one edge
  int e0 = rowptr[node], e1 = rowptr[node+1];
  int mid = e0 + (int)(packed[node] >> 16);

  float4 accp = {0.f,0.f,0.f,0.f}, accl = {0.f,0.f,0.f,0.f};
  float2 tp01 = {0.f,0.f}, tl01 = {0.f,0.f};
  float tp2 = 0.f, tl2 = 0.f;

  auto body = [&](int idx, int lim, float4& ac, float2& t01, float& t2){
    float mm = 0.f; int s = 0;
    if (idx < lim){ mm = 1.f; s = eidx[idx]; }
    uint2 u = *(const uint2*)((const char*)ggA + ((size_t)s<<6) + (sub<<3));
    float2 f0 = __half22float2(*(__half2*)&u.x);
    float2 f1 = __half22float2(*(__half2*)&u.y);
    ac.x += mm*f0.x; ac.y += mm*f0.y; ac.z += mm*f1.x; ac.w += mm*f1.y;
    if (sub == 0 && idx < lim){
      uint2 ut = *(const uint2*)((const char*)ggT + ((size_t)s<<3));
      float2 g0 = __half22float2(*(__half2*)&ut.x);
      float2 g1 = __half22float2(*(__half2*)&ut.y);
      t01.x += g0.x; t01.y += g0.y; t2 += g1.x;
    }
  };

  int e = e0;
  #pragma unroll 2
  for (; e+8 <= mid; e+=8) body(e+g, mid, accp, tp01, tp2);
  if (e < mid) body(e+g, mid, accp, tp01, tp2);
  e = mid;
  #pragma unroll 2
  for (; e+8 <= e1; e+=8) body(e+g, e1, accl, tl01, tl2);
  if (e < e1) body(e+g, e1, accl, tl01, tl2);

  // butterfly across the 8 groups (xor 8/16/32 keeps sub fixed)
  for (int off=8; off<64; off<<=1){
    accp.x += __shfl_xor(accp.x, off, 64); accp.y += __shfl_xor(accp.y, off, 64);
    accp.z += __shfl_xor(accp.z, off, 64); accp.w += __shfl_xor(accp.w, off, 64);
    accl.x += __shfl_xor(accl.x, off, 64); accl.y += __shfl_xor(accl.y, off, 64);
    accl.z += __shfl_xor(accl.z, off, 64); accl.w += __shfl_xor(accl.w, off, 64);
    tp01.x += __shfl_xor(tp01.x, off, 64); tp01.y += __shfl_xor(tp01.y, off, 64);
    tl01.x += __shfl_xor(tl01.x, off, 64); tl01.y += __shfl_xor(tl01.y, off, 64);
    tp2 += __shfl_xor(tp2, off, 64); tl2 += __shfl_xor(tl2, off, 64);
  }

  // redistribute to 35-lane layout: lane d holds dim d
  int srcl = ln >> 2;
  float p0 = __shfl(accp.x, srcl, 64), p1 = __shfl(accp.y, srcl, 64);
  float p2 = __shfl(accp.z, srcl, 64), p3 = __shfl(accp.w, srcl, 64);
  float l0 = __shfl(accl.x, srcl, 64), l1 = __shfl(accl.y, srcl, 64);
  float l2 = __shfl(accl.z, srcl, 64), l3 = __shfl(accl.w, srcl, 64);
  float zp = (ln&2) ? ((ln&1)? p3 : p2) : ((ln&1)? p1 : p0);
  float zl = (ln&2) ? ((ln&1)? l3 : l2) : ((ln&1)? l1 : l0);
  float tpa = __shfl(tp01.x, 0, 64), tpb = __shfl(tp01.y, 0, 64), tpc = __shfl(tp2, 0, 64);
  float tla = __shfl(tl01.x, 0, 64), tlb = __shfl(tl01.y, 0, 64), tlc = __shfl(tl2, 0, 64);
  if (ln == 32){ zp = tpa; zl = tla; }
  else if (ln == 33){ zp = tpb; zl = tlb; }
  else if (ln == 34){ zp = tpc; zl = tlc; }

  // self-loop (premultiplied values) + dinv[dst] factor
  int spl = split[node];
  float dp = dinvp[node], dl = dinvl[node];
  const __half* pA = spl ? ggA : ownA;  const __half* pT = spl ? ggT : ownT;
  const __half* lA = spl ? ownA : ggA;  const __half* lT = spl ? ownT : ggT;
  float sp = 0.f, sl = 0.f;
  if (ln < 32){
    sp = __half2float(pA[(size_t)node*32 + ln]);
    sl = __half2float(lA[(size_t)node*32 + ln]);
  } else if (ln < DD){
    sp = __half2float(pT[(size_t)node*4 + (ln-32)]);
    sl = __half2float(lT[(size_t)node*4 + (ln-32)]);
  }
  bool act = ln < DD;
  float zpf = act ? dp*(zp + sp) : 0.f;
  float zlf = act ? dl*(zl + sl) : 0.f;

  // matvec via shfl broadcast
  float op = 0.f, ol = 0.f;
  for (int j=0;j<DD;++j){
    float zpj = __shfl(zpf, j, 64);
    float zlj = __shfl(zlf, j, 64);
    float wp = act ? Wp[j*DD+ln] : 0.f;
    float wl = act ? Wl[j*DD+ln] : 0.f;
    op += zpj*wp; ol += zlj*wl;
  }
  float opb = act ? fmaxf(op + bp[ln], 0.f) : 0.f;
  float olb = act ? fmaxf(ol + bl[ln], 0.f) : 0.f;

  if (last){
    float a0 = __shfl(opb, (2*ln)&63, 64), a1 = __shfl(opb, (2*ln+1)&63, 64);
    float b0 = __shfl(olb, (2*ln)&63, 64), b1 = __shfl(olb, (2*ln+1)&63, 64);
    if (ln < 18){
      *(__half2*)(hpF + (size_t)node*GW + 2*ln) = __floats2half2_rn(a0,a1);
      *(__half2*)(hlF + (size_t)node*GW + 2*ln) = __floats2half2_rn(b0,b1);
    }
  } else {
    float ggv  = spl ? dp*opb : dl*olb;   // selected stack, premultiplied
    float ownv = spl ? dl*olb : dp*opb;   // other stack, premultiplied
    float a0 = __shfl(ggv, (2*ln)&63, 64), a1 = __shfl(ggv, (2*ln+1)&63, 64);
    float b0 = __shfl(ownv, (2*ln)&63, 64), b1 = __shfl(ownv, (2*ln+1)&63, 64);
    if (ln < 16){
      *(__half2*)(ggAo + (size_t)node*32 + 2*ln) = __floats2half2_rn(a0,a1);
      *(__half2*)(ownAo + (size_t)node*32 + 2*ln) = __floats2half2_rn(b0,b1);
    } else if (ln < 18){
      *(__half2*)(ggTo + (size_t)node*4 + 2*(ln-16)) = __floats2half2_rn(a0,a1);
      *(__half2*)(ownTo + (size_t)node*4 + 2*(ln-16)) = __floats2half2_rn(b0,b1);
    }
  }
}

// ---------------- batch pooling (fp16 in, f32 out) ----------------
__global__ void k_bsum(const __half* __restrict__ gp, const __half* __restrict__ gl,
                       const int* __restrict__ bstart, const int* __restrict__ bend,
                       float* pro, float* lig){
  __shared__ float sp[4][GW], sl[4][GW];
  int b = blockIdx.x;
  int w = threadIdx.x>>6, ln = threadIdx.x&63;
  int s0 = bstart[b], s1 = bend[b];
  float apx=0.f, apy=0.f, alx=0.f, aly=0.f;
  if (ln < 18){
    for (int n=s0+w; n<s1; n+=4){
      float2 a = __half22float2(*(const __half2*)(gp + (size_t)n*GW + 2*ln));
      float2 c = __half22float2(*(const __half2*)(gl + (size_t)n*GW + 2*ln));
      apx+=a.x; apy+=a.y; alx+=c.x; aly+=c.y;
    }
    sp[w][2*ln]=apx; sp[w][2*ln+1]=apy;
    sl[w][2*ln]=alx; sl[w][2*ln+1]=aly;
  }
  __syncthreads();
  if (threadIdx.x < DD){
    int d = threadIdx.x;
    pro[b*DD+d] = sp[0][d]+sp[1][d]+sp[2][d]+sp[3][d];
    lig[b*DD+d] = sl[0][d]+sl[1][d]+sl[2][d]+sl[3][d];
  }
}

// ---------------- reverse LSTM common chain (zero inputs, steps t=139..2) -------
__global__ void k_lstm_common(const float* __restrict__ wib, const float* __restrict__ whb,
                              const float* __restrict__ bib, const float* __restrict__ bhb,
                              float* hbc, float* hbcst){
  __shared__ float h[DD], cc[DD], g[4*DD];
  int t = threadIdx.x;
  if (t < DD){ h[t]=0.f; cc[t]=0.f; }
  __syncthreads();
  for (int k=1;k<=TT-2;++k){
    if (t < 4*DD){
      float acc = bib[t]+bhb[t];
      for (int m=0;m<DD;++m) acc += whb[t*DD+m]*h[m];
      g[t]=acc;
    }
    __syncthreads();
    if (t < DD){
      float ig=g[t], fg=g[DD+t], gg=g[2*DD+t], og=g[3*DD+t];
      float cv = sigf(fg)*cc[t] + sigf(ig)*tanhf(gg);
      float hv = sigf(og)*tanhf(cv);
      cc[t]=cv; h[t]=hv;
      hbc[(TT-k)*DD + t] = hv;
    }
    __syncthreads();
  }
  if (t<DD){ hbcst[t]=h[t]; hbcst[DD+t]=cc[t]; }
}

// ---------------- per-batch LSTM: fwd 140 steps + bwd 2-step tail ---------------
__global__ void k_lstm_batch(const float* __restrict__ lig, const float* __restrict__ pro,
   const float* __restrict__ wif, const float* __restrict__ whf,
   const float* __restrict__ bif, const float* __restrict__ bhf,
   const float* __restrict__ wib, const float* __restrict__ whb,
   const float* __restrict__ bib, const float* __restrict__ bhb,
   const float* __restrict__ hbc, const float* __restrict__ hbcst, float* outseq){
  __shared__ float x0[DD], x1[DD], h[DD], cc[DD], g[4*DD], xg0[4*DD], xg1[4*DD];
  int b = blockIdx.x, t = threadIdx.x;
  if (t<DD){ x0[t]=lig[b*DD+t]; x1[t]=pro[b*DD+t]; h[t]=0.f; cc[t]=0.f; }
  __syncthreads();
  if (t<4*DD){
    float a0=0.f, a1=0.f;
    for (int m=0;m<DD;++m){ a0 += wif[t*DD+m]*x0[m]; a1 += wif[t*DD+m]*x1[m]; }
    xg0[t]=a0; xg1[t]=a1;
  }
  __syncthreads();
  float* outb = outseq + (size_t)b*TT*DHX;
  for (int tt=0;tt<TT;++tt){
    if (t<4*DD){
      float acc = bif[t]+bhf[t] + (tt==0? xg0[t] : (tt==1? xg1[t] : 0.f));
      for (int m=0;m<DD;++m) acc += whf[t*DD+m]*h[m];
      g[t]=acc;
    }
    __syncthreads();
    if (t<DD){
      float ig=g[t], fg=g[DD+t], gg=g[2*DD+t], og=g[3*DD+t];
      float cv = sigf(fg)*cc[t]+sigf(ig)*tanhf(gg);
      float hv = sigf(og)*tanhf(cv);
      cc[t]=cv; h[t]=hv;
      outb[tt*DHX + t] = hv;
    }
    __syncthreads();
  }
  if (t<4*DD){
    float a0=0.f, a1=0.f;
    for (int m=0;m<DD;++m){ a0 += wib[t*DD+m]*x0[m]; a1 += wib[t*DD+m]*x1[m]; }
    xg0[t]=a0; xg1[t]=a1;
  }
  if (t<DD){ h[t]=hbcst[t]; cc[t]=hbcst[DD+t]; }
  __syncthreads();
  for (int step=0; step<2; ++step){
    int tt = 1-step;
    if (t<4*DD){
      float acc = bib[t]+bhb[t] + (tt==1? xg1[t] : xg0[t]);
      for (int m=0;m<DD;++m) acc += whb[t*DD+m]*h[m];
      g[t]=acc;
    }
    __syncthreads();
    if (t<DD){
      float ig=g[t], fg=g[DD+t], gg=g[2*DD+t], og=g[3*DD+t];
      float cv = sigf(fg)*cc[t]+sigf(ig)*tanhf(gg);
      float hv = sigf(og)*tanhf(cv);
      cc[t]=cv; h[t]=hv;
      outb[tt*DHX + DD + t] = hv;
    }
    __syncthreads();
  }
  for (int idx=t; idx<(TT-2)*DD; idx+=blockDim.x){
    int tt = 2 + idx/DD, d = idx%DD;
    outb[tt*DHX + DD + d] = hbc[tt*DD + d];
  }
}

// ---------------- attention (mask-collapsed) per batch ----------------
__global__ void __launch_bounds__(256)
k_attn(const float* __restrict__ outseq,
  const float* __restrict__ Wq, const float* __restrict__ bq,
  const float* __restrict__ Wk, const float* __restrict__ bk,
  const float* __restrict__ Wv, const float* __restrict__ bv,
  const float* __restrict__ Wo, const float* __restrict__ bo,
  float* PT, int B){
  __shared__ float so[TT*DHX];
  __shared__ float sk[TT*DHX];
  __shared__ float sv[TT*DHX];
  __shared__ float sq[2*DHX];
  __shared__ float es[TT];
  __shared__ float red[4];
  __shared__ float ctx[3*DHX];
  int b = blockIdx.x, tid = threadIdx.x;
  const float* ob = outseq + (size_t)b*TT*DHX;
  for (int i=tid;i<TT*DHX;i+=256) so[i]=ob[i];
  __syncthreads();
  for (int i=tid;i<TT*DHX;i+=256){
    int s=i/DHX, d=i%DHX;
    float ak=bk[d], av=bv[d];
    const float* r = so + s*DHX;
    for (int j=0;j<DHX;++j){ float o=r[j]; ak += o*Wk[d*DHX+j]; av += o*Wv[d*DHX+j]; }
    sk[i]=ak; sv[i]=av;
  }
  for (int i=tid;i<2*DHX;i+=256){
    int s=i/DHX, d=i%DHX;
    float a=bq[d];
    for (int j=0;j<DHX;++j) a += so[s*DHX+j]*Wq[d*DHX+j];
    sq[i]=a;
  }
  __syncthreads();
  const float scale = 0.11952286093343936f;
  for (int s=tid;s<TT;s+=256){
    float a=0.f;
    for (int j=0;j<DHX;++j) a += sq[DHX+j]*sk[s*DHX+j];
    es[s] = a*scale;
  }
  __syncthreads();
  if (tid < 64){
    float m=-1e30f;
    for (int s=tid;s<TT;s+=64) if (s!=1) m=fmaxf(m, es[s]);
    for (int o=32;o;o>>=1) m = fmaxf(m, __shfl_xor(m,o,64));
    if (tid==0) red[0]=m;
  }
  __syncthreads();
  float m = red[0];
  for (int s=tid;s<TT;s+=256) es[s] = (s==1)? 0.f : expf(es[s]-m);
  __syncthreads();
  if (tid<64){
    float sum=0.f;
    for (int s=tid;s<TT;s+=64) sum+=es[s];
    for (int o=32;o;o>>=1) sum += __shfl_xor(sum,o,64);
    if (tid==0) red[1]=sum;
  }
  if (tid==0){
    float s00=0.f,s01=0.f;
    for (int j=0;j<DHX;++j){ s00 += sq[j]*sk[j]; s01 += sq[j]*sk[DHX+j]; }
    s00*=scale; s01*=scale;
    float mm=fmaxf(s00,s01);
    float e0=expf(s00-mm), e1=expf(s01-mm);
    red[2]=e0/(e0+e1); red[3]=e1/(e0+e1);
  }
  __syncthreads();
  float inv = 1.0f/red[1];
  float a0=red[2], a1=red[3];
  if (tid < DHX){
    int d=tid;
    float c1=0.f;
    for (int s=0;s<TT;++s) c1 += es[s]*sv[s*DHX+d];
    ctx[DHX+d] = c1*inv;
    ctx[d] = a0*sv[d] + a1*sv[DHX+d];
    ctx[2*DHX+d] = sv[DHX+d];
  }
  __syncthreads();
  for (int i=tid;i<3*DHX;i+=256){
    int tt=i/DHX, d=i%DHX;
    float a=bo[d];
    const float* cv = ctx + tt*DHX;
    for (int j=0;j<DHX;++j) a += Wo[d*DHX+j]*cv[j];
    PT[(size_t)i*B + b] = a;
  }
}

// ---------------- W1 tail-block sum (cols 140..9799 collapse onto p2) ----------
__global__ void k_w1s(const float* __restrict__ W1, float* w1s){
  __shared__ float sh[DHX];
  int j = blockIdx.x; int tid = threadIdx.x;   // 140 threads
  int d = tid % DHX, half = tid / DHX;
  const float* r = W1 + (size_t)j*(TT*DHX);
  float acc = 0.f;
  int t0 = half ? 71 : 2, t1 = half ? 140 : 71;
  for (int t=t0; t<t1; ++t) acc += r[t*DHX+d];
  if (half==0) sh[d] = acc;
  __syncthreads();
  if (half) w1s[(size_t)j*DHX+d] = sh[d] + acc;
}

// ---------------- y = P @ [W1a|W1b|W1s]^T + b1 ----------------
__global__ void k_y(const float* __restrict__ PT, const float* __restrict__ W1,
                    const float* __restrict__ w1s, const float* __restrict__ b1,
                    float* yT, int B){
  int j = blockIdx.x; int b = threadIdx.x;
  const float* r = W1 + (size_t)j*(TT*DHX);
  float acc = b1[j];
  for (int i=0;i<2*DHX;++i) acc += r[i]*PT[(size_t)i*B+b];
  const float* rs = w1s + (size_t)j*DHX;
  for (int i=0;i<DHX;++i) acc += rs[i]*PT[(size_t)(2*DHX+i)*B+b];
  yT[(size_t)j*B+b] = acc;
}

// ---------------- BatchNorm(train) + Mish + W2 reduce ----------------
__global__ void k_bn(const float* __restrict__ yT, const float* __restrict__ gamma,
                     const float* __restrict__ beta, const float* __restrict__ W2,
                     float* out, int B, int J){
  __shared__ float red_s[2];
  int b = threadIdx.x;
  int lane = b & 63, w = b>>6;
  float acc = 0.f;
  int j0 = blockIdx.x*32;
  float invB = 1.0f/(float)B;
  for (int jj=0;jj<32;++jj){
    int j = j0+jj; if (j>=J) break;
    float v = yT[(size_t)j*B + b];
    float s=v;
    for (int o=32;o;o>>=1) s += __shfl_xor(s,o,64);
    if (lane==0) red_s[w]=s;
    __syncthreads();
    float mu = (red_s[0]+red_s[1]) * invB;
    __syncthreads();
    float dd = v-mu;
    float q=dd*dd;
    for (int o=32;o;o>>=1) q += __shfl_xor(q,o,64);
    if (lane==0) red_s[w]=q;
    __syncthreads();
    float var = (red_s[0]+red_s[1]) * invB;
    __syncthreads();
    float xn = dd*rsqrtf(var+1e-5f)*gamma[j]+beta[j];
    float sp = (xn>20.f)? xn : log1pf(expf(xn));
    float mish = xn*tanhf(sp);
    acc += mish*W2[j];
  }
  atomicAdd(&out[b], acc);
}

extern "C" void kernel_launch(void* const* d_in, const int* in_sizes, int n_in,
                              void* d_out, int out_size, void* d_ws, size_t ws_size,
                              hipStream_t stream)
{
  const float* x    = (const float*)d_in[0];
  const int*   ei   = (const int*)  d_in[1];
  const int*   split= (const int*)  d_in[2];
  const int*   batch= (const int*)  d_in[3];
  const float* Wp   = (const float*)d_in[4];
  const float* bp   = (const float*)d_in[5];
  const float* Wl   = (const float*)d_in[6];
  const float* bl   = (const float*)d_in[7];
  const float* wif  = (const float*)d_in[8];
  const float* whf  = (const float*)d_in[9];
  const float* bif  = (const float*)d_in[10];
  const float* bhf  = (const float*)d_in[11];
  const float* wib  = (const float*)d_in[12];
  const float* whb  = (const float*)d_in[13];
  const float* bib  = (const float*)d_in[14];
  const float* bhb  = (const float*)d_in[15];
  const float* Wq   = (const float*)d_in[16];
  const float* bq   = (const float*)d_in[17];
  const float* Wk   = (const float*)d_in[18];
  const float* bk   = (const float*)d_in[19];
  const float* Wv   = (const float*)d_in[20];
  const float* bv   = (const float*)d_in[21];
  const float* Wo   = (const float*)d_in[22];
  const float* bo   = (const float*)d_in[23];
  const float* W1   = (const float*)d_in[24];
  const float* b1   = (const float*)d_in[25];
  const float* gam  = (const float*)d_in[26];
  const float* bet  = (const float*)d_in[27];
  const float* W2   = (const float*)d_in[28];
  const float* b2   = (const float*)d_in[29];
  float* out = (float*)d_out;

  const int N = in_sizes[0]/DD;
  const int E = in_sizes[1]/2;
  const int B = out_size;
  const int J = in_sizes[25];
  (void)n_in; (void)ws_size;

  char* ws = (char*)d_ws;
  size_t off = 0;
  auto carve = [&](size_t bytes)->void*{ void* p = ws + off; off = (off + bytes + 255) & ~(size_t)255; return p; };
  __half* ggA_A  = (__half*)carve((size_t)N*32*2);
  __half* ggT_A  = (__half*)carve((size_t)N*4*2);
  __half* ownA_A = (__half*)carve((size_t)N*32*2);
  __half* ownT_A = (__half*)carve((size_t)N*4*2);
  __half* ggA_B  = (__half*)carve((size_t)N*32*2);
  __half* ggT_B  = (__half*)carve((size_t)N*4*2);
  __half* ownA_B = (__half*)carve((size_t)N*32*2);
  __half* ownT_B = (__half*)carve((size_t)N*4*2);
  __half* hpF    = (__half*)carve((size_t)N*GW*2);
  __half* hlF    = (__half*)carve((size_t)N*GW*2);
  float* dinvp = (float*)carve((size_t)N*4);
  float* dinvl = (float*)carve((size_t)N*4);
  int*   cnt   = (int*)  carve((size_t)N*4);
  unsigned int* packed = (unsigned int*)carve((size_t)N*4);
  int*   rowptr= (int*)  carve((size_t)(N+1)*4);
  int*   curP  = (int*)  carve((size_t)N*4);
  int*   curL  = (int*)  carve((size_t)N*4);
  int*   bsum  = (int*)  carve(4096);
  int*   eidx  = (int*)  carve((size_t)E*4);
  float* pro   = (float*)carve((size_t)B*DD*4);
  float* lig   = (float*)carve((size_t)B*DD*4);
  int*   bstart= (int*)  carve((size_t)B*4);
  int*   bend  = (int*)  carve((size_t)B*4);
  float* hbc   = (float*)carve((size_t)TT*DD*4);
  float* hbcst = (float*)carve(2*DD*4);
  float* outseq= (float*)carve((size_t)B*TT*DHX*4);
  float* PT    = (float*)carve((size_t)3*DHX*B*4);
  float* w1s   = (float*)carve((size_t)J*DHX*4);
  float* yT    = (float*)carve((size_t)J*B*4);

  int mx = (N>B)?N:B;
  k_init<<<(mx+255)/256, 256, 0, stream>>>(packed, bstart, bend, out, b2, N, B);
  k_edge_deg<<<(E+255)/256, 256, 0, stream>>>(ei, split, packed, E);
  k_node1<<<(N+255)/256, 256, 0, stream>>>(packed, dinvp, dinvl, cnt, batch, bstart, bend, N);
  int n4 = (N+3)/4;
  int nbA = (n4+255)/256;
  k_scanA<<<nbA, 256, 0, stream>>>(cnt, rowptr, bsum, N);
  k_scanB<<<1, 512, 0, stream>>>(bsum, nbA);
  k_scanC<<<(N+255)/256, 256, 0, stream>>>(rowptr, curP, curL, bsum, packed, N, E);
  k_fill<<<(E+255)/256, 256, 0, stream>>>(ei, split, curP, curL, eidx, E);
  k_pack0<<<((size_t)N*18+255)/256, 256, 0, stream>>>(x, dinvp, dinvl, split,
      ggA_A, ggT_A, ownA_A, ownT_A, N);

  const __half *giA=ggA_A, *giT=ggT_A, *oiA=ownA_A, *oiT=ownT_A;
  __half *goA=ggA_B, *goT=ggT_B, *ooA=ownA_B, *ooT=ownT_B;
  for (int i=0;i<5;++i){
    int last = (i==4);
    k_gcn<<<(N+3)/4, 256, 0, stream>>>(giA, giT, oiA, oiT,
      goA, goT, ooA, ooT, hpF, hlF,
      rowptr, eidx, packed, split, dinvp, dinvl,
      Wp + (size_t)i*DD*DD, bp + (size_t)i*DD, Wl + (size_t)i*DD*DD, bl + (size_t)i*DD,
      N, last);
    const __half* t;
    t = giA; giA = goA; goA = (__half*)t;
    t = giT; giT = goT; goT = (__half*)t;
    t = oiA; oiA = ooA; ooA = (__half*)t;
    t = oiT; oiT = ooT; ooT = (__half*)t;
  }

  k_bsum<<<B, 256, 0, stream>>>(hpF, hlF, bstart, bend, pro, lig);
  k_lstm_common<<<1, 192, 0, stream>>>(wib, whb, bib, bhb, hbc, hbcst);
  k_lstm_batch<<<B, 192, 0, stream>>>(lig, pro, wif, whf, bif, bhf, wib, whb, bib, bhb, hbc, hbcst, outseq);
  k_attn<<<B, 256, 0, stream>>>(outseq, Wq, bq, Wk, bk, Wv, bv, Wo, bo, PT, B);
  k_w1s<<<J, 140, 0, stream>>>(W1, w1s);
  k_y<<<J, B, 0, stream>>>(PT, W1, w1s, b1, yT, B);
  k_bn<<<(J+31)/32, B, 0, stream>>>(yT, gam, bet, W2, out, B, J);
}